// Round 4
// baseline (1275.575 us; speedup 1.0000x reference)
//
#include <hip/hip_runtime.h>

#define BN 8192
#define DD 128
#define ALPHA 2.0f
#define BETA 50.0f
#define BASE 0.5f
#define MARGIN 0.1f
#define ROWT 64
#define COLT 64
#define NSPLIT 8
#define CPS (BN / NSPLIT)

typedef __attribute__((ext_vector_type(8))) short short8v;
typedef __attribute__((ext_vector_type(4))) float f32x4;
typedef __attribute__((ext_vector_type(4))) int int4v;

__device__ __forceinline__ unsigned short f2bf(float x) {
    union { float f; unsigned u; } q; q.f = x;
    unsigned r = q.u + 0x7fffu + ((q.u >> 16) & 1u);   // RNE
    return (unsigned short)(r >> 16);
}

// ---------------- K0: fp32 -> bf16 ----------------
__global__ __launch_bounds__(256) void k0_cvt(const float* __restrict__ emb,
                                              unsigned short* __restrict__ ebf) {
    int idx = (blockIdx.x * 256 + threadIdx.x) * 4;   // grid = BN*DD/1024 = 1024
    float4 v = *(const float4*)(emb + idx);
    ushort4 o;
    o.x = f2bf(v.x); o.y = f2bf(v.y); o.z = f2bf(v.z); o.w = f2bf(v.w);
    *(ushort4*)(ebf + idx) = o;
}

// ---------------- K1: pos_min + has_pos/has_neg ----------------
__global__ __launch_bounds__(256) void k1_posmin(const float* __restrict__ emb,
                                                 const int* __restrict__ lab,
                                                 float* __restrict__ pos_min,
                                                 int* __restrict__ flags) {
    __shared__ float ei[DD];
    __shared__ float red[256];
    __shared__ int redi[256];
    const int i = blockIdx.x;
    const int t = threadIdx.x;
    if (t < DD / 4) ((float4*)ei)[t] = ((const float4*)(emb + (size_t)i * DD))[t];
    __syncthreads();
    const int li = lab[i];
    float lmin = __builtin_inff();
    int fl = 0;
    for (int j = t; j < BN; j += 256) {
        int lj = lab[j];
        if (lj == li) {
            if (j != i) {
                fl |= 1;
                const float4* ej = (const float4*)(emb + (size_t)j * DD);
                float s = 0.f;
#pragma unroll 8
                for (int k = 0; k < DD / 4; ++k) {
                    float4 a = ((const float4*)ei)[k];
                    float4 b = ej[k];
                    s = fmaf(a.x, b.x, s); s = fmaf(a.y, b.y, s);
                    s = fmaf(a.z, b.z, s); s = fmaf(a.w, b.w, s);
                }
                lmin = fminf(lmin, s);
            }
        } else {
            fl |= 2;
        }
    }
    red[t] = lmin; redi[t] = fl;
    __syncthreads();
    for (int s = 128; s > 0; s >>= 1) {
        if (t < s) { red[t] = fminf(red[t], red[t + s]); redi[t] |= redi[t + s]; }
        __syncthreads();
    }
    if (t == 0) { pos_min[i] = red[0]; flags[i] = redi[0]; }
}

// ---------------- K2: MFMA main pass (neg_max / neg_sum partials) ----------------
__global__ __launch_bounds__(256) void k2_main(const unsigned short* __restrict__ ebf,
                                               const int* __restrict__ lab,
                                               const float* __restrict__ pos_min,
                                               float* __restrict__ nmax_part,
                                               float* __restrict__ nsum_part) {
    __shared__ unsigned short Bs[COLT * DD];   // 16 KB, XOR-swizzled in 16B units
    __shared__ int labs[COLT];

    const int rb = blockIdx.x / NSPLIT;
    const int split = blockIdx.x % NSPLIT;
    const int row0 = rb * ROWT;
    const int col0 = split * CPS;
    const int t = threadIdx.x;
    const int w = t >> 6;        // wave 0..3
    const int l = t & 63;        // lane
    const int l15 = l & 15;
    const int lq = l >> 4;       // lane quarter 0..3

    // A fragments: wave w owns rows row0 + w*16 + (l&15); K=128 -> 4 k-steps
    const int arow = row0 + w * 16 + l15;
    short8v afrag[4];
#pragma unroll
    for (int ks = 0; ks < 4; ++ks)
        afrag[ks] = *(const short8v*)(ebf + (size_t)arow * DD + ks * 32 + lq * 8);

    // per-lane row metadata: acc reg q maps to row row0 + w*16 + lq*4 + q (C/D layout)
    float thr[4]; int labr[4];
#pragma unroll
    for (int q = 0; q < 4; ++q) {
        int r = row0 + w * 16 + lq * 4 + q;
        thr[q] = pos_min[r] - MARGIN;
        labr[q] = lab[r];
    }

    float nmax[4] = { -__builtin_inff(), -__builtin_inff(), -__builtin_inff(), -__builtin_inff() };
    float nsum[4] = { 0.f, 0.f, 0.f, 0.f };

    for (int ct = 0; ct < CPS; ct += COLT) {
        const int cbase = col0 + ct;
        __syncthreads();
        // stage B tile (64 rows x 128 bf16), 1024 16B-units, swizzled dest
        for (int u = t; u < 1024; u += 256) {
            int c = u >> 4, kb = u & 15;
            int4v v = *(const int4v*)(ebf + (size_t)(cbase + c) * DD + kb * 8);
            int byte = (c << 8) + (kb << 4);
            byte ^= (c & 7) << 4;
            *(int4v*)((char*)Bs + byte) = v;
        }
        if (t < COLT) labs[t] = lab[cbase + t];
        __syncthreads();

#pragma unroll
        for (int cf = 0; cf < 4; ++cf) {
            const int c = cf * 16 + l15;
            short8v bfrag[4];
#pragma unroll
            for (int ks = 0; ks < 4; ++ks) {
                int byte = (c << 8) + ks * 64 + lq * 16;
                byte ^= (c & 7) << 4;
                bfrag[ks] = *(const short8v*)((const char*)Bs + byte);
            }
            f32x4 acc = { 0.f, 0.f, 0.f, 0.f };
#pragma unroll
            for (int ks = 0; ks < 4; ++ks)
                acc = __builtin_amdgcn_mfma_f32_16x16x32_bf16(afrag[ks], bfrag[ks], acc, 0, 0, 0);

            const int labc = labs[cf * 16 + l15];
#pragma unroll
            for (int q = 0; q < 4; ++q) {
                float s = acc[q];
                bool keep = (labc != labr[q]) && (s > thr[q]);
                float e = __expf(BETA * (s - BASE));
                nmax[q] = keep ? fmaxf(nmax[q], s) : nmax[q];
                nsum[q] += keep ? e : 0.f;
            }
        }
    }

    // reduce across the 16 lanes (l&15) sharing each C-row; fixed order -> deterministic
#pragma unroll
    for (int q = 0; q < 4; ++q) {
        float m = nmax[q], sm = nsum[q];
#pragma unroll
        for (int d = 1; d < 16; d <<= 1) {
            m = fmaxf(m, __shfl_xor(m, d));
            sm += __shfl_xor(sm, d);
        }
        if (l15 == 0) {
            int r = row0 + w * 16 + lq * 4 + q;
            nmax_part[(size_t)r * NSPLIT + split] = m;
            nsum_part[(size_t)r * NSPLIT + split] = sm;
        }
    }
}

// ---------------- K3: combine partials + pos_sum + row loss ----------------
__global__ __launch_bounds__(256) void k3_pos(const float* __restrict__ emb,
                                              const int* __restrict__ lab,
                                              const int* __restrict__ flags,
                                              const float* __restrict__ nmax_part,
                                              const float* __restrict__ nsum_part,
                                              float* __restrict__ row_loss,
                                              float* __restrict__ row_cnt) {
    __shared__ float ei[DD];
    __shared__ float red[256];
    __shared__ float s_negmax, s_negsum;
    const int i = blockIdx.x;
    const int t = threadIdx.x;
    if (t < DD / 4) ((float4*)ei)[t] = ((const float4*)(emb + (size_t)i * DD))[t];
    if (t == 0) {
        float nm = -__builtin_inff(), ns = 0.f;
#pragma unroll
        for (int p = 0; p < NSPLIT; ++p) {
            nm = fmaxf(nm, nmax_part[(size_t)i * NSPLIT + p]);
            ns += nsum_part[(size_t)i * NSPLIT + p];
        }
        s_negmax = nm; s_negsum = ns;
    }
    __syncthreads();
    const int li = lab[i];
    const float pthr = s_negmax + MARGIN;   // -inf stays -inf -> no pos kept
    float psum = 0.f;
    for (int j = t; j < BN; j += 256) {
        if (lab[j] == li && j != i) {
            const float4* ej = (const float4*)(emb + (size_t)j * DD);
            float s = 0.f;
#pragma unroll 8
            for (int k = 0; k < DD / 4; ++k) {
                float4 a = ((const float4*)ei)[k];
                float4 b = ej[k];
                s = fmaf(a.x, b.x, s); s = fmaf(a.y, b.y, s);
                s = fmaf(a.z, b.z, s); s = fmaf(a.w, b.w, s);
            }
            if (s < pthr) psum += expf(-ALPHA * (s - BASE));
        }
    }
    red[t] = psum;
    __syncthreads();
    for (int s = 128; s > 0; s >>= 1) {
        if (t < s) red[t] += red[t + s];
        __syncthreads();
    }
    if (t == 0) {
        float ps = red[0];
        int fl = flags[i];
        bool valid = (fl & 1) && (fl & 2) && (s_negmax > -3.0e38f) && (ps > 0.f);
        float loss = log1pf(ps) / ALPHA + log1pf(s_negsum) / BETA;
        row_loss[i] = valid ? loss : 0.f;
        row_cnt[i]  = valid ? 1.f : 0.f;
    }
}

// ---------------- K4: final deterministic reduction ----------------
__global__ __launch_bounds__(256) void k4_final(const float* __restrict__ row_loss,
                                                const float* __restrict__ row_cnt,
                                                float* __restrict__ out) {
    __shared__ float rl[256], rc[256];
    const int t = threadIdx.x;
    float a = 0.f, c = 0.f;
    for (int j = t; j < BN; j += 256) { a += row_loss[j]; c += row_cnt[j]; }
    rl[t] = a; rc[t] = c;
    __syncthreads();
    for (int s = 128; s > 0; s >>= 1) {
        if (t < s) { rl[t] += rl[t + s]; rc[t] += rc[t + s]; }
        __syncthreads();
    }
    if (t == 0) out[0] = (rc[0] > 0.f) ? rl[0] / fmaxf(rc[0], 1.f) : 0.f;
}

extern "C" void kernel_launch(void* const* d_in, const int* in_sizes, int n_in,
                              void* d_out, int out_size, void* d_ws, size_t ws_size,
                              hipStream_t stream) {
    const float* emb = (const float*)d_in[0];
    const int* lab = (const int*)d_in[1];
    float* out = (float*)d_out;

    char* ws = (char*)d_ws;
    unsigned short* ebf = (unsigned short*)ws;                 // BN*DD*2 = 2 MB
    float* pos_min   = (float*)(ws + (size_t)BN * DD * 2);
    int*   flags     = (int*)(pos_min + BN);
    float* nmax_part = (float*)(flags + BN);
    float* nsum_part = nmax_part + (size_t)BN * NSPLIT;
    float* row_loss  = nsum_part + (size_t)BN * NSPLIT;
    float* row_cnt   = row_loss + BN;

    k0_cvt<<<BN * DD / 1024, 256, 0, stream>>>(emb, ebf);
    k1_posmin<<<BN, 256, 0, stream>>>(emb, lab, pos_min, flags);
    k2_main<<<(BN / ROWT) * NSPLIT, 256, 0, stream>>>(ebf, lab, pos_min, nmax_part, nsum_part);
    k3_pos<<<BN, 256, 0, stream>>>(emb, lab, flags, nmax_part, nsum_part, row_loss, row_cnt);
    k4_final<<<1, 256, 0, stream>>>(row_loss, row_cnt, out);
}

// Round 5
// 139.300 us; speedup vs baseline: 9.1571x; 9.1571x over previous
//
#include <hip/hip_runtime.h>

#define BN 8192
#define DD 128
#define NC 64
#define ALPHA 2.0f
#define BETA 50.0f
#define BASE 0.5f
#define MARGIN 0.1f
#define ROWT 64
#define COLT 64
#define NSPLIT 8
#define CPS (BN / NSPLIT)

typedef __attribute__((ext_vector_type(8))) short short8v;
typedef __attribute__((ext_vector_type(4))) float f32x4;
typedef __attribute__((ext_vector_type(4))) int int4v;

__device__ __forceinline__ unsigned short f2bf(float x) {
    union { float f; unsigned u; } q; q.f = x;
    unsigned r = q.u + 0x7fffu + ((q.u >> 16) & 1u);   // RNE
    return (unsigned short)(r >> 16);
}

// ---------------- K0: fp32 -> bf16 ----------------
__global__ __launch_bounds__(256) void k0_cvt(const float* __restrict__ emb,
                                              unsigned short* __restrict__ ebf) {
    int idx = (blockIdx.x * 256 + threadIdx.x) * 4;
    float4 v = *(const float4*)(emb + idx);
    ushort4 o;
    o.x = f2bf(v.x); o.y = f2bf(v.y); o.z = f2bf(v.z); o.w = f2bf(v.w);
    *(ushort4*)(ebf + idx) = o;
}

// ---------------- KB: class bucketing (deterministic, stable) ----------------
__global__ __launch_bounds__(256) void kb_count(const int* __restrict__ lab,
                                                int* __restrict__ offsets) {
    __shared__ int hist[NC];
    const int t = threadIdx.x;
    if (t < NC) hist[t] = 0;
    __syncthreads();
    for (int j = t; j < BN; j += 256) atomicAdd(&hist[lab[j]], 1);
    __syncthreads();
    if (t == 0) {
        int acc = 0;
        for (int c = 0; c < NC; ++c) { offsets[c] = acc; acc += hist[c]; }
        offsets[NC] = acc;
    }
}

__global__ __launch_bounds__(256) void kb_fill(const int* __restrict__ lab,
                                               const int* __restrict__ offsets,
                                               int* __restrict__ memb) {
    __shared__ int wt[4];
    __shared__ int s_cur;
    const int c = blockIdx.x;
    const int t = threadIdx.x;
    const int w = t >> 6, lane = t & 63;
    if (t == 0) s_cur = offsets[c];
    __syncthreads();
    for (int j0 = 0; j0 < BN; j0 += 256) {
        const int j = j0 + t;
        const bool m = (lab[j] == c);
        unsigned long long bal = __ballot(m);
        int below = __popcll(bal & ((1ULL << lane) - 1ULL));
        if (lane == 0) wt[w] = __popcll(bal);
        __syncthreads();
        int wbase = 0;
        for (int p = 0; p < w; ++p) wbase += wt[p];
        const int tot = wt[0] + wt[1] + wt[2] + wt[3];
        const int base = s_cur;
        if (m) memb[base + wbase + below] = j;
        __syncthreads();
        if (t == 0) s_cur = base + tot;
        __syncthreads();
    }
}

// ---------------- K1c: per-class pos_min via MFMA ----------------
__global__ __launch_bounds__(256) void k1_class(const unsigned short* __restrict__ ebf,
                                                const int* __restrict__ offsets,
                                                const int* __restrict__ memb,
                                                float* __restrict__ pos_min) {
    __shared__ unsigned short Bs[COLT * DD];
    __shared__ int mcol[COLT];
    const int c = blockIdx.x;
    const int off = offsets[c];
    const int M = offsets[c + 1] - off;
    if (M == 0) return;
    const int t = threadIdx.x, w = t >> 6, l = t & 63, l15 = l & 15, lq = l >> 4;

    for (int r0 = 0; r0 < M; r0 += ROWT) {
        const int slot_a = r0 + w * 16 + l15;
        const int arow = memb[off + (slot_a < M ? slot_a : M - 1)];
        short8v afrag[4];
#pragma unroll
        for (int ks = 0; ks < 4; ++ks)
            afrag[ks] = *(const short8v*)(ebf + (size_t)arow * DD + ks * 32 + lq * 8);

        int mr[4]; float pmin[4];
#pragma unroll
        for (int q = 0; q < 4; ++q) {
            int sq = r0 + w * 16 + lq * 4 + q;
            mr[q] = (sq < M) ? memb[off + sq] : -1;
            pmin[q] = __builtin_inff();
        }

        for (int c0 = 0; c0 < M; c0 += COLT) {
            __syncthreads();
            for (int u = t; u < 1024; u += 256) {
                int cc = u >> 4, kb = u & 15;
                int cs = c0 + cc;
                int crow = memb[off + (cs < M ? cs : M - 1)];
                int4v v = *(const int4v*)(ebf + (size_t)crow * DD + kb * 8);
                int byte = (cc << 8) + (kb << 4);
                byte ^= (cc & 7) << 4;
                *(int4v*)((char*)Bs + byte) = v;
            }
            if (t < COLT) mcol[t] = (c0 + t < M) ? memb[off + c0 + t] : -1;
            __syncthreads();

#pragma unroll
            for (int cf = 0; cf < 4; ++cf) {
                const int cc = cf * 16 + l15;
                short8v bfrag[4];
#pragma unroll
                for (int ks = 0; ks < 4; ++ks) {
                    int byte = (cc << 8) + ks * 64 + lq * 16;
                    byte ^= (cc & 7) << 4;
                    bfrag[ks] = *(const short8v*)((const char*)Bs + byte);
                }
                f32x4 acc = { 0.f, 0.f, 0.f, 0.f };
#pragma unroll
                for (int ks = 0; ks < 4; ++ks)
                    acc = __builtin_amdgcn_mfma_f32_16x16x32_bf16(afrag[ks], bfrag[ks], acc, 0, 0, 0);
                const int mc = mcol[cf * 16 + l15];
#pragma unroll
                for (int q = 0; q < 4; ++q)
                    if (mc >= 0 && mc != mr[q]) pmin[q] = fminf(pmin[q], acc[q]);
            }
        }

#pragma unroll
        for (int q = 0; q < 4; ++q) {
            float m = pmin[q];
#pragma unroll
            for (int d = 1; d < 16; d <<= 1) m = fminf(m, __shfl_xor(m, d));
            if (l15 == 0 && mr[q] >= 0) pos_min[mr[q]] = m;
        }
    }
}

// ---------------- K2: MFMA main pass (neg_max / neg_sum partials) ----------------
__global__ __launch_bounds__(256) void k2_main(const unsigned short* __restrict__ ebf,
                                               const int* __restrict__ lab,
                                               const float* __restrict__ pos_min,
                                               float* __restrict__ nmax_part,
                                               float* __restrict__ nsum_part) {
    __shared__ unsigned short Bs[COLT * DD];
    __shared__ int labs[COLT];

    const int rb = blockIdx.x / NSPLIT;
    const int split = blockIdx.x % NSPLIT;
    const int row0 = rb * ROWT;
    const int col0 = split * CPS;
    const int t = threadIdx.x;
    const int w = t >> 6;
    const int l = t & 63;
    const int l15 = l & 15;
    const int lq = l >> 4;

    const int arow = row0 + w * 16 + l15;
    short8v afrag[4];
#pragma unroll
    for (int ks = 0; ks < 4; ++ks)
        afrag[ks] = *(const short8v*)(ebf + (size_t)arow * DD + ks * 32 + lq * 8);

    float thr[4]; int labr[4];
#pragma unroll
    for (int q = 0; q < 4; ++q) {
        int r = row0 + w * 16 + lq * 4 + q;
        thr[q] = pos_min[r] - MARGIN;
        labr[q] = lab[r];
    }

    float nmax[4] = { -__builtin_inff(), -__builtin_inff(), -__builtin_inff(), -__builtin_inff() };
    float nsum[4] = { 0.f, 0.f, 0.f, 0.f };

    for (int ct = 0; ct < CPS; ct += COLT) {
        const int cbase = col0 + ct;
        __syncthreads();
        for (int u = t; u < 1024; u += 256) {
            int c = u >> 4, kb = u & 15;
            int4v v = *(const int4v*)(ebf + (size_t)(cbase + c) * DD + kb * 8);
            int byte = (c << 8) + (kb << 4);
            byte ^= (c & 7) << 4;
            *(int4v*)((char*)Bs + byte) = v;
        }
        if (t < COLT) labs[t] = lab[cbase + t];
        __syncthreads();

#pragma unroll
        for (int cf = 0; cf < 4; ++cf) {
            const int c = cf * 16 + l15;
            short8v bfrag[4];
#pragma unroll
            for (int ks = 0; ks < 4; ++ks) {
                int byte = (c << 8) + ks * 64 + lq * 16;
                byte ^= (c & 7) << 4;
                bfrag[ks] = *(const short8v*)((const char*)Bs + byte);
            }
            f32x4 acc = { 0.f, 0.f, 0.f, 0.f };
#pragma unroll
            for (int ks = 0; ks < 4; ++ks)
                acc = __builtin_amdgcn_mfma_f32_16x16x32_bf16(afrag[ks], bfrag[ks], acc, 0, 0, 0);

            const int labc = labs[cf * 16 + l15];
#pragma unroll
            for (int q = 0; q < 4; ++q) {
                float s = acc[q];
                bool keep = (labc != labr[q]) && (s > thr[q]);
                float e = __expf(BETA * (s - BASE));
                nmax[q] = keep ? fmaxf(nmax[q], s) : nmax[q];
                nsum[q] += keep ? e : 0.f;
            }
        }
    }

#pragma unroll
    for (int q = 0; q < 4; ++q) {
        float m = nmax[q], sm = nsum[q];
#pragma unroll
        for (int d = 1; d < 16; d <<= 1) {
            m = fmaxf(m, __shfl_xor(m, d));
            sm += __shfl_xor(sm, d);
        }
        if (l15 == 0) {
            int r = row0 + w * 16 + lq * 4 + q;
            nmax_part[(size_t)r * NSPLIT + split] = m;
            nsum_part[(size_t)r * NSPLIT + split] = sm;
        }
    }
}

// ---------------- K3c: per-class pos_sum + row loss ----------------
__global__ __launch_bounds__(256) void k3_class(const unsigned short* __restrict__ ebf,
                                                const int* __restrict__ offsets,
                                                const int* __restrict__ memb,
                                                const float* __restrict__ nmax_part,
                                                const float* __restrict__ nsum_part,
                                                float* __restrict__ row_loss,
                                                float* __restrict__ row_cnt) {
    __shared__ unsigned short Bs[COLT * DD];
    __shared__ int mcol[COLT];
    const int c = blockIdx.x;
    const int off = offsets[c];
    const int M = offsets[c + 1] - off;
    if (M == 0) return;
    const int t = threadIdx.x, w = t >> 6, l = t & 63, l15 = l & 15, lq = l >> 4;

    for (int r0 = 0; r0 < M; r0 += ROWT) {
        const int slot_a = r0 + w * 16 + l15;
        const int arow = memb[off + (slot_a < M ? slot_a : M - 1)];
        short8v afrag[4];
#pragma unroll
        for (int ks = 0; ks < 4; ++ks)
            afrag[ks] = *(const short8v*)(ebf + (size_t)arow * DD + ks * 32 + lq * 8);

        int mr[4]; float pthr[4], nmv[4], nsv[4], psum[4];
#pragma unroll
        for (int q = 0; q < 4; ++q) {
            int sq = r0 + w * 16 + lq * 4 + q;
            mr[q] = (sq < M) ? memb[off + sq] : -1;
            psum[q] = 0.f;
            float nm = -__builtin_inff(), ns = 0.f;
            if (mr[q] >= 0) {
#pragma unroll
                for (int p = 0; p < NSPLIT; ++p) {
                    nm = fmaxf(nm, nmax_part[(size_t)mr[q] * NSPLIT + p]);
                    ns += nsum_part[(size_t)mr[q] * NSPLIT + p];
                }
            }
            nmv[q] = nm; nsv[q] = ns;
            pthr[q] = nm + MARGIN;   // -inf stays -inf
        }

        for (int c0 = 0; c0 < M; c0 += COLT) {
            __syncthreads();
            for (int u = t; u < 1024; u += 256) {
                int cc = u >> 4, kb = u & 15;
                int cs = c0 + cc;
                int crow = memb[off + (cs < M ? cs : M - 1)];
                int4v v = *(const int4v*)(ebf + (size_t)crow * DD + kb * 8);
                int byte = (cc << 8) + (kb << 4);
                byte ^= (cc & 7) << 4;
                *(int4v*)((char*)Bs + byte) = v;
            }
            if (t < COLT) mcol[t] = (c0 + t < M) ? memb[off + c0 + t] : -1;
            __syncthreads();

#pragma unroll
            for (int cf = 0; cf < 4; ++cf) {
                const int cc = cf * 16 + l15;
                short8v bfrag[4];
#pragma unroll
                for (int ks = 0; ks < 4; ++ks) {
                    int byte = (cc << 8) + ks * 64 + lq * 16;
                    byte ^= (cc & 7) << 4;
                    bfrag[ks] = *(const short8v*)((const char*)Bs + byte);
                }
                f32x4 acc = { 0.f, 0.f, 0.f, 0.f };
#pragma unroll
                for (int ks = 0; ks < 4; ++ks)
                    acc = __builtin_amdgcn_mfma_f32_16x16x32_bf16(afrag[ks], bfrag[ks], acc, 0, 0, 0);
                const int mc = mcol[cf * 16 + l15];
#pragma unroll
                for (int q = 0; q < 4; ++q) {
                    float s = acc[q];
                    if (mc >= 0 && mc != mr[q] && s < pthr[q])
                        psum[q] += expf(-ALPHA * (s - BASE));
                }
            }
        }

#pragma unroll
        for (int q = 0; q < 4; ++q) {
            float ps = psum[q];
#pragma unroll
            for (int d = 1; d < 16; d <<= 1) ps += __shfl_xor(ps, d);
            if (l15 == 0 && mr[q] >= 0) {
                bool valid = (M >= 2) && (M < BN) && (nmv[q] > -3.0e38f) && (ps > 0.f);
                float loss = log1pf(ps) / ALPHA + log1pf(nsv[q]) / BETA;
                row_loss[mr[q]] = valid ? loss : 0.f;
                row_cnt[mr[q]]  = valid ? 1.f : 0.f;
            }
        }
    }
}

// ---------------- K4: final deterministic reduction ----------------
__global__ __launch_bounds__(256) void k4_final(const float* __restrict__ row_loss,
                                                const float* __restrict__ row_cnt,
                                                float* __restrict__ out) {
    __shared__ float rl[256], rc[256];
    const int t = threadIdx.x;
    float a = 0.f, c = 0.f;
    for (int j = t; j < BN; j += 256) { a += row_loss[j]; c += row_cnt[j]; }
    rl[t] = a; rc[t] = c;
    __syncthreads();
    for (int s = 128; s > 0; s >>= 1) {
        if (t < s) { rl[t] += rl[t + s]; rc[t] += rc[t + s]; }
        __syncthreads();
    }
    if (t == 0) out[0] = (rc[0] > 0.f) ? rl[0] / fmaxf(rc[0], 1.f) : 0.f;
}

extern "C" void kernel_launch(void* const* d_in, const int* in_sizes, int n_in,
                              void* d_out, int out_size, void* d_ws, size_t ws_size,
                              hipStream_t stream) {
    const float* emb = (const float*)d_in[0];
    const int* lab = (const int*)d_in[1];
    float* out = (float*)d_out;

    char* ws = (char*)d_ws;
    unsigned short* ebf = (unsigned short*)ws;                   // 2 MB
    float* pos_min   = (float*)(ws + (size_t)BN * DD * 2);
    float* nmax_part = pos_min + BN;
    float* nsum_part = nmax_part + (size_t)BN * NSPLIT;
    float* row_loss  = nsum_part + (size_t)BN * NSPLIT;
    float* row_cnt   = row_loss + BN;
    int*   offsets   = (int*)(row_cnt + BN);                     // NC+1 ints
    int*   memb      = offsets + (NC + 1);                       // BN ints

    k0_cvt<<<BN * DD / 1024, 256, 0, stream>>>(emb, ebf);
    kb_count<<<1, 256, 0, stream>>>(lab, offsets);
    kb_fill<<<NC, 256, 0, stream>>>(lab, offsets, memb);
    k1_class<<<NC, 256, 0, stream>>>(ebf, offsets, memb, pos_min);
    k2_main<<<(BN / ROWT) * NSPLIT, 256, 0, stream>>>(ebf, lab, pos_min, nmax_part, nsum_part);
    k3_class<<<NC, 256, 0, stream>>>(ebf, offsets, memb, nmax_part, nsum_part, row_loss, row_cnt);
    k4_final<<<1, 256, 0, stream>>>(row_loss, row_cnt, out);
}

// Round 6
// 103.486 us; speedup vs baseline: 12.3261x; 1.3461x over previous
//
#include <hip/hip_runtime.h>

#define BN 8192
#define DD 128
#define NC 64
#define ALPHA 2.0f
#define BETA 50.0f
#define BASE 0.5f
#define MARGIN 0.1f
#define ROWT 64
#define COLT 64
#define NSPLIT 8
#define CPS (BN / NSPLIT)

// exp/exp2 folding constants: exp(B*(s-BASE)) = exp2(s*B*log2e - B*BASE*log2e)
#define NEG_K1 72.13475204444817f     /* BETA*log2(e) */
#define NEG_K0 -36.067376022224085f   /* -BETA*BASE*log2(e) */
#define POS_K1 -2.8853900817779268f   /* -ALPHA*log2(e) */
#define POS_K0 1.4426950408889634f    /* ALPHA*BASE*log2(e) */

typedef __attribute__((ext_vector_type(8))) short short8v;
typedef __attribute__((ext_vector_type(4))) float f32x4;
typedef __attribute__((ext_vector_type(4))) int int4v;

__device__ __forceinline__ float exp2_fast(float x) {
#if __has_builtin(__builtin_amdgcn_exp2f)
    return __builtin_amdgcn_exp2f(x);
#else
    return __expf(x * 0.6931471805599453f);
#endif
}

__device__ __forceinline__ unsigned short f2bf(float x) {
    union { float f; unsigned u; } q; q.f = x;
    unsigned r = q.u + 0x7fffu + ((q.u >> 16) & 1u);   // RNE
    return (unsigned short)(r >> 16);
}

// ---------------- K0: fp32 -> bf16 ----------------
__global__ __launch_bounds__(256) void k0_cvt(const float* __restrict__ emb,
                                              unsigned short* __restrict__ ebf) {
    int idx = (blockIdx.x * 256 + threadIdx.x) * 4;
    float4 v = *(const float4*)(emb + idx);
    ushort4 o;
    o.x = f2bf(v.x); o.y = f2bf(v.y); o.z = f2bf(v.z); o.w = f2bf(v.w);
    *(ushort4*)(ebf + idx) = o;
}

// ---------------- KB: fused class bucketing (64 blocks, no serial prefix) ----------------
__global__ __launch_bounds__(256) void kb_bucket(const int* __restrict__ lab,
                                                 int* __restrict__ offsets,
                                                 int* __restrict__ memb) {
    __shared__ int red[256];
    __shared__ int wt[4];
    __shared__ int s_cur;
    const int c = blockIdx.x;
    const int t = threadIdx.x;
    const int w = t >> 6, lane = t & 63;

    // offset of class c = #(labels < c), computed locally
    int below = 0;
    for (int j = t; j < BN; j += 256) below += (lab[j] < c) ? 1 : 0;
    red[t] = below;
    __syncthreads();
    for (int s = 128; s > 0; s >>= 1) {
        if (t < s) red[t] += red[t + s];
        __syncthreads();
    }
    const int base0 = red[0];
    if (t == 0) {
        offsets[c] = base0;
        if (c == 0) offsets[NC] = BN;   // labels always in [0,NC)
        s_cur = base0;
    }
    __syncthreads();

    // stable fill in ascending j order via ballot compaction
    for (int j0 = 0; j0 < BN; j0 += 256) {
        const int j = j0 + t;
        const bool m = (lab[j] == c);
        unsigned long long bal = __ballot(m);
        int bel = __popcll(bal & ((1ULL << lane) - 1ULL));
        if (lane == 0) wt[w] = __popcll(bal);
        __syncthreads();
        int wbase = 0;
        for (int p = 0; p < w; ++p) wbase += wt[p];
        const int tot = wt[0] + wt[1] + wt[2] + wt[3];
        const int base = s_cur;
        if (m) memb[base + wbase + bel] = j;
        __syncthreads();
        if (t == 0) s_cur = base + tot;
        __syncthreads();
    }
}

// ---------------- K1c: per-class pos_min via MFMA (grid = NC x 2 row-splits) ----------------
__global__ __launch_bounds__(256) void k1_class(const unsigned short* __restrict__ ebf,
                                                const int* __restrict__ offsets,
                                                const int* __restrict__ memb,
                                                float* __restrict__ pos_min) {
    __shared__ __align__(16) unsigned short Bs[COLT * DD];
    __shared__ int mcol[COLT];
    const int c = blockIdx.x & (NC - 1);
    const int rs = blockIdx.x >> 6;
    const int off = offsets[c];
    const int M = offsets[c + 1] - off;
    if (M == 0) return;
    const int t = threadIdx.x, w = t >> 6, l = t & 63, l15 = l & 15, lq = l >> 4;

    for (int r0 = rs * ROWT; r0 < M; r0 += 2 * ROWT) {
        const int slot_a = r0 + w * 16 + l15;
        const int arow = memb[off + (slot_a < M ? slot_a : M - 1)];
        short8v afrag[4];
#pragma unroll
        for (int ks = 0; ks < 4; ++ks)
            afrag[ks] = *(const short8v*)(ebf + (size_t)arow * DD + ks * 32 + lq * 8);

        int mr[4]; float pmin[4];
#pragma unroll
        for (int q = 0; q < 4; ++q) {
            int sq = r0 + w * 16 + lq * 4 + q;
            mr[q] = (sq < M) ? memb[off + sq] : -1;
            pmin[q] = __builtin_inff();
        }

        for (int c0 = 0; c0 < M; c0 += COLT) {
            __syncthreads();
            for (int u = t; u < 1024; u += 256) {
                int cc = u >> 4, kb = u & 15;
                int cs = c0 + cc;
                int crow = memb[off + (cs < M ? cs : M - 1)];
                int4v v = *(const int4v*)(ebf + (size_t)crow * DD + kb * 8);
                int byte = (cc << 8) + (kb << 4);
                byte ^= (cc & 7) << 4;
                *(int4v*)((char*)Bs + byte) = v;
            }
            if (t < COLT) mcol[t] = (c0 + t < M) ? memb[off + c0 + t] : -1;
            __syncthreads();

#pragma unroll
            for (int cf = 0; cf < 4; ++cf) {
                const int cc = cf * 16 + l15;
                short8v bfrag[4];
#pragma unroll
                for (int ks = 0; ks < 4; ++ks) {
                    int byte = (cc << 8) + ks * 64 + lq * 16;
                    byte ^= (cc & 7) << 4;
                    bfrag[ks] = *(const short8v*)((const char*)Bs + byte);
                }
                f32x4 acc = { 0.f, 0.f, 0.f, 0.f };
#pragma unroll
                for (int ks = 0; ks < 4; ++ks)
                    acc = __builtin_amdgcn_mfma_f32_16x16x32_bf16(afrag[ks], bfrag[ks], acc, 0, 0, 0);
                const int mc = mcol[cf * 16 + l15];
#pragma unroll
                for (int q = 0; q < 4; ++q) {
                    float sv = (mc >= 0 && mc != mr[q]) ? acc[q] : __builtin_inff();
                    pmin[q] = fminf(pmin[q], sv);
                }
            }
        }

#pragma unroll
        for (int q = 0; q < 4; ++q) {
            float m = pmin[q];
#pragma unroll
            for (int d = 1; d < 16; d <<= 1) m = fminf(m, __shfl_xor(m, d));
            if (l15 == 0 && mr[q] >= 0) pos_min[mr[q]] = m;
        }
    }
}

// ---------------- K2: MFMA main pass, double-buffered reg-staged pipeline ----------------
__global__ __launch_bounds__(256) void k2_main(const unsigned short* __restrict__ ebf,
                                               const int* __restrict__ lab,
                                               const float* __restrict__ pos_min,
                                               float* __restrict__ nmax_part,
                                               float* __restrict__ nsum_part) {
    __shared__ __align__(16) unsigned short Bs[2][COLT * DD];   // 2 x 16 KB
    __shared__ int labs[2][COLT];

    const int rb = blockIdx.x / NSPLIT;
    const int split = blockIdx.x % NSPLIT;
    const int row0 = rb * ROWT;
    const int col0 = split * CPS;
    const int t = threadIdx.x;
    const int w = t >> 6;
    const int l = t & 63;
    const int l15 = l & 15;
    const int lq = l >> 4;

    const int arow = row0 + w * 16 + l15;
    short8v afrag[4];
#pragma unroll
    for (int ks = 0; ks < 4; ++ks)
        afrag[ks] = *(const short8v*)(ebf + (size_t)arow * DD + ks * 32 + lq * 8);

    float thr[4]; int labr[4];
#pragma unroll
    for (int q = 0; q < 4; ++q) {
        int r = row0 + w * 16 + lq * 4 + q;
        thr[q] = pos_min[r] - MARGIN;
        labr[q] = lab[r];
    }

    float nmax[4] = { -__builtin_inff(), -__builtin_inff(), -__builtin_inff(), -__builtin_inff() };
    float nsum[4] = { 0.f, 0.f, 0.f, 0.f };

    // per-thread staging unit addresses: u = t + k*256 -> col cc = u>>4, 16B chunk kb = u&15
    const int NT = CPS / COLT;   // 16 tiles
    int4v stg[4]; int stglab;

    // prologue: load tile 0 and write to buffer 0
    {
        const int cbase = col0;
#pragma unroll
        for (int k = 0; k < 4; ++k) {
            int u = t + k * 256, cc = u >> 4, kb = u & 15;
            stg[k] = *(const int4v*)(ebf + (size_t)(cbase + cc) * DD + kb * 8);
        }
        stglab = lab[cbase + (t & (COLT - 1))];
#pragma unroll
        for (int k = 0; k < 4; ++k) {
            int u = t + k * 256, cc = u >> 4, kb = u & 15;
            int byte = (cc << 8) + (kb << 4);
            byte ^= (cc & 7) << 4;
            *(int4v*)((char*)&Bs[0][0] + byte) = stg[k];
        }
        if (t < COLT) labs[0][t] = stglab;
    }

    int cur = 0;
    for (int tt = 0; tt < NT; ++tt) {
        __syncthreads();   // Bs[cur] ready; all prior reads of Bs[cur^1] complete

        // issue next tile's global loads (latency hidden under compute below)
        if (tt + 1 < NT) {
            const int cbase = col0 + (tt + 1) * COLT;
#pragma unroll
            for (int k = 0; k < 4; ++k) {
                int u = t + k * 256, cc = u >> 4, kb = u & 15;
                stg[k] = *(const int4v*)(ebf + (size_t)(cbase + cc) * DD + kb * 8);
            }
            stglab = lab[cbase + (t & (COLT - 1))];
        }

        // compute from Bs[cur]
        const char* bsc = (const char*)&Bs[cur][0];
#pragma unroll
        for (int cf = 0; cf < 4; ++cf) {
            const int cc = cf * 16 + l15;
            short8v bfrag[4];
#pragma unroll
            for (int ks = 0; ks < 4; ++ks) {
                int byte = (cc << 8) + ks * 64 + lq * 16;
                byte ^= (cc & 7) << 4;
                bfrag[ks] = *(const short8v*)(bsc + byte);
            }
            f32x4 acc = { 0.f, 0.f, 0.f, 0.f };
#pragma unroll
            for (int ks = 0; ks < 4; ++ks)
                acc = __builtin_amdgcn_mfma_f32_16x16x32_bf16(afrag[ks], bfrag[ks], acc, 0, 0, 0);

            const int labc = labs[cur][cf * 16 + l15];
#pragma unroll
            for (int q = 0; q < 4; ++q) {
                float s = acc[q];
                // mask to -inf: excluded from max, exp2(-inf)=0 excluded from sum
                float sv = (labc != labr[q] && s > thr[q]) ? s : -__builtin_inff();
                nmax[q] = fmaxf(nmax[q], sv);
                nsum[q] += exp2_fast(fmaf(sv, NEG_K1, NEG_K0));
            }
        }

        // write next tile into the other buffer (safe: its readers finished before this iter's barrier)
        if (tt + 1 < NT) {
#pragma unroll
            for (int k = 0; k < 4; ++k) {
                int u = t + k * 256, cc = u >> 4, kb = u & 15;
                int byte = (cc << 8) + (kb << 4);
                byte ^= (cc & 7) << 4;
                *(int4v*)((char*)&Bs[cur ^ 1][0] + byte) = stg[k];
            }
            if (t < COLT) labs[cur ^ 1][t] = stglab;
        }
        cur ^= 1;
    }

#pragma unroll
    for (int q = 0; q < 4; ++q) {
        float m = nmax[q], sm = nsum[q];
#pragma unroll
        for (int d = 1; d < 16; d <<= 1) {
            m = fmaxf(m, __shfl_xor(m, d));
            sm += __shfl_xor(sm, d);
        }
        if (l15 == 0) {
            int r = row0 + w * 16 + lq * 4 + q;
            nmax_part[(size_t)r * NSPLIT + split] = m;
            nsum_part[(size_t)r * NSPLIT + split] = sm;
        }
    }
}

// ---------------- K3c: per-class pos_sum + row loss (grid = NC x 2 row-splits) ----------------
__global__ __launch_bounds__(256) void k3_class(const unsigned short* __restrict__ ebf,
                                                const int* __restrict__ offsets,
                                                const int* __restrict__ memb,
                                                const float* __restrict__ nmax_part,
                                                const float* __restrict__ nsum_part,
                                                float* __restrict__ row_loss,
                                                float* __restrict__ row_cnt) {
    __shared__ __align__(16) unsigned short Bs[COLT * DD];
    __shared__ int mcol[COLT];
    const int c = blockIdx.x & (NC - 1);
    const int rs = blockIdx.x >> 6;
    const int off = offsets[c];
    const int M = offsets[c + 1] - off;
    if (M == 0) return;
    const int t = threadIdx.x, w = t >> 6, l = t & 63, l15 = l & 15, lq = l >> 4;

    for (int r0 = rs * ROWT; r0 < M; r0 += 2 * ROWT) {
        const int slot_a = r0 + w * 16 + l15;
        const int arow = memb[off + (slot_a < M ? slot_a : M - 1)];
        short8v afrag[4];
#pragma unroll
        for (int ks = 0; ks < 4; ++ks)
            afrag[ks] = *(const short8v*)(ebf + (size_t)arow * DD + ks * 32 + lq * 8);

        int mr[4]; float pthr[4], nmv[4], nsv[4], psum[4];
#pragma unroll
        for (int q = 0; q < 4; ++q) {
            int sq = r0 + w * 16 + lq * 4 + q;
            mr[q] = (sq < M) ? memb[off + sq] : -1;
            psum[q] = 0.f;
            float nm = -__builtin_inff(), ns = 0.f;
            if (mr[q] >= 0) {
#pragma unroll
                for (int p = 0; p < NSPLIT; ++p) {
                    nm = fmaxf(nm, nmax_part[(size_t)mr[q] * NSPLIT + p]);
                    ns += nsum_part[(size_t)mr[q] * NSPLIT + p];
                }
            }
            nmv[q] = nm; nsv[q] = ns;
            pthr[q] = nm + MARGIN;   // -inf stays -inf -> no pos kept
        }

        for (int c0 = 0; c0 < M; c0 += COLT) {
            __syncthreads();
            for (int u = t; u < 1024; u += 256) {
                int cc = u >> 4, kb = u & 15;
                int cs = c0 + cc;
                int crow = memb[off + (cs < M ? cs : M - 1)];
                int4v v = *(const int4v*)(ebf + (size_t)crow * DD + kb * 8);
                int byte = (cc << 8) + (kb << 4);
                byte ^= (cc & 7) << 4;
                *(int4v*)((char*)Bs + byte) = v;
            }
            if (t < COLT) mcol[t] = (c0 + t < M) ? memb[off + c0 + t] : -1;
            __syncthreads();

#pragma unroll
            for (int cf = 0; cf < 4; ++cf) {
                const int cc = cf * 16 + l15;
                short8v bfrag[4];
#pragma unroll
                for (int ks = 0; ks < 4; ++ks) {
                    int byte = (cc << 8) + ks * 64 + lq * 16;
                    byte ^= (cc & 7) << 4;
                    bfrag[ks] = *(const short8v*)((const char*)Bs + byte);
                }
                f32x4 acc = { 0.f, 0.f, 0.f, 0.f };
#pragma unroll
                for (int ks = 0; ks < 4; ++ks)
                    acc = __builtin_amdgcn_mfma_f32_16x16x32_bf16(afrag[ks], bfrag[ks], acc, 0, 0, 0);
                const int mc = mcol[cf * 16 + l15];
#pragma unroll
                for (int q = 0; q < 4; ++q) {
                    float s = acc[q];
                    // mask to +inf: exp2(fma(+inf, neg, pos)) = exp2(-inf) = 0
                    float sv = (mc >= 0 && mc != mr[q] && s < pthr[q]) ? s : __builtin_inff();
                    psum[q] += exp2_fast(fmaf(sv, POS_K1, POS_K0));
                }
            }
        }

#pragma unroll
        for (int q = 0; q < 4; ++q) {
            float ps = psum[q];
#pragma unroll
            for (int d = 1; d < 16; d <<= 1) ps += __shfl_xor(ps, d);
            if (l15 == 0 && mr[q] >= 0) {
                bool valid = (M >= 2) && (M < BN) && (nmv[q] > -3.0e38f) && (ps > 0.f);
                float loss = log1pf(ps) / ALPHA + log1pf(nsv[q]) / BETA;
                row_loss[mr[q]] = valid ? loss : 0.f;
                row_cnt[mr[q]]  = valid ? 1.f : 0.f;
            }
        }
    }
}

// ---------------- K4: final deterministic reduction ----------------
__global__ __launch_bounds__(256) void k4_final(const float* __restrict__ row_loss,
                                                const float* __restrict__ row_cnt,
                                                float* __restrict__ out) {
    __shared__ float rl[256], rc[256];
    const int t = threadIdx.x;
    float a = 0.f, c = 0.f;
    for (int j = t; j < BN; j += 256) { a += row_loss[j]; c += row_cnt[j]; }
    rl[t] = a; rc[t] = c;
    __syncthreads();
    for (int s = 128; s > 0; s >>= 1) {
        if (t < s) { rl[t] += rl[t + s]; rc[t] += rc[t + s]; }
        __syncthreads();
    }
    if (t == 0) out[0] = (rc[0] > 0.f) ? rl[0] / fmaxf(rc[0], 1.f) : 0.f;
}

extern "C" void kernel_launch(void* const* d_in, const int* in_sizes, int n_in,
                              void* d_out, int out_size, void* d_ws, size_t ws_size,
                              hipStream_t stream) {
    const float* emb = (const float*)d_in[0];
    const int* lab = (const int*)d_in[1];
    float* out = (float*)d_out;

    char* ws = (char*)d_ws;
    unsigned short* ebf = (unsigned short*)ws;                   // 2 MB
    float* pos_min   = (float*)(ws + (size_t)BN * DD * 2);
    float* nmax_part = pos_min + BN;
    float* nsum_part = nmax_part + (size_t)BN * NSPLIT;
    float* row_loss  = nsum_part + (size_t)BN * NSPLIT;
    float* row_cnt   = row_loss + BN;
    int*   offsets   = (int*)(row_cnt + BN);                     // NC+1 ints
    int*   memb      = offsets + (NC + 1);                       // BN ints

    k0_cvt<<<BN * DD / 1024, 256, 0, stream>>>(emb, ebf);
    kb_bucket<<<NC, 256, 0, stream>>>(lab, offsets, memb);
    k1_class<<<NC * 2, 256, 0, stream>>>(ebf, offsets, memb, pos_min);
    k2_main<<<(BN / ROWT) * NSPLIT, 256, 0, stream>>>(ebf, lab, pos_min, nmax_part, nsum_part);
    k3_class<<<NC * 2, 256, 0, stream>>>(ebf, offsets, memb, nmax_part, nsum_part, row_loss, row_cnt);
    k4_final<<<1, 256, 0, stream>>>(row_loss, row_cnt, out);
}

// Round 7
// 100.467 us; speedup vs baseline: 12.6965x; 1.0301x over previous
//
#include <hip/hip_runtime.h>

#define BN 8192
#define DD 128
#define NC 64
#define ALPHA 2.0f
#define BETA 50.0f
#define BASE 0.5f
#define MARGIN 0.1f
#define ROWT 128
#define COLT 64
#define NSPLIT 16
#define CPS (BN / NSPLIT)

// exp/exp2 folding: exp(B*(s-BASE)) = exp2(fma(s, B*log2e, -B*BASE*log2e))
#define NEG_K1 72.13475204444817f     /* BETA*log2(e) */
#define NEG_K0 -36.067376022224085f   /* -BETA*BASE*log2(e) */
#define POS_K1 -2.8853900817779268f   /* -ALPHA*log2(e) */
#define POS_K0 1.4426950408889634f    /* ALPHA*BASE*log2(e) */

typedef __attribute__((ext_vector_type(8))) short short8v;
typedef __attribute__((ext_vector_type(4))) float f32x4;
typedef __attribute__((ext_vector_type(4))) int int4v;

__device__ __forceinline__ float exp2_fast(float x) {
#if __has_builtin(__builtin_amdgcn_exp2f)
    return __builtin_amdgcn_exp2f(x);
#else
    return __expf(x * 0.6931471805599453f);
#endif
}

__device__ __forceinline__ unsigned short f2bf(float x) {
    union { float f; unsigned u; } q; q.f = x;
    unsigned r = q.u + 0x7fffu + ((q.u >> 16) & 1u);   // RNE
    return (unsigned short)(r >> 16);
}

// ---------------- K0: fused fp32->bf16 convert (blocks 0..1023) + class bucketing (blocks 1024..1087) ----------------
__global__ __launch_bounds__(256) void k0_fused(const float* __restrict__ emb,
                                                const int* __restrict__ lab,
                                                unsigned short* __restrict__ ebf,
                                                int* __restrict__ offsets,
                                                int* __restrict__ memb) {
    const int b = blockIdx.x;
    const int t = threadIdx.x;
    if (b < BN * DD / 1024) {
        int idx = (b * 256 + t) * 4;
        float4 v = *(const float4*)(emb + idx);
        ushort4 o;
        o.x = f2bf(v.x); o.y = f2bf(v.y); o.z = f2bf(v.z); o.w = f2bf(v.w);
        *(ushort4*)(ebf + idx) = o;
    } else if (t < 64) {
        // single-wave, sync-free stable bucketing for class c
        const int c = b - BN * DD / 1024;
        int below = 0;
        for (int j = t; j < BN; j += 64) below += (lab[j] < c) ? 1 : 0;
#pragma unroll
        for (int d = 1; d < 64; d <<= 1) below += __shfl_xor(below, d);
        if (t == 0) {
            offsets[c] = below;
            if (c == 0) offsets[NC] = BN;   // labels in [0, NC)
        }
        int cur = below;
        for (int j0 = 0; j0 < BN; j0 += 64) {
            const bool m = (lab[j0 + t] == c);
            unsigned long long bal = __ballot(m);
            int bel = __popcll(bal & ((1ULL << t) - 1ULL));
            if (m) memb[cur + bel] = j0 + t;
            cur += __popcll(bal);
        }
    }
}

// ---------------- K1c: per-class pos_min via MFMA (grid = NC x 2 row-splits) ----------------
__global__ __launch_bounds__(256) void k1_class(const unsigned short* __restrict__ ebf,
                                                const int* __restrict__ offsets,
                                                const int* __restrict__ memb,
                                                float* __restrict__ pos_min) {
    __shared__ __align__(16) unsigned short Bs[COLT * DD];
    __shared__ int mcol[COLT];
    const int c = blockIdx.x & (NC - 1);
    const int rs = blockIdx.x >> 6;
    const int off = offsets[c];
    const int M = offsets[c + 1] - off;
    if (M == 0) return;
    const int t = threadIdx.x, w = t >> 6, l = t & 63, l15 = l & 15, lq = l >> 4;

    for (int r0 = rs * 64; r0 < M; r0 += 128) {
        const int slot_a = r0 + w * 16 + l15;
        const int arow = memb[off + (slot_a < M ? slot_a : M - 1)];
        short8v afrag[4];
#pragma unroll
        for (int ks = 0; ks < 4; ++ks)
            afrag[ks] = *(const short8v*)(ebf + (size_t)arow * DD + ks * 32 + lq * 8);

        int mr[4]; float pmin[4];
#pragma unroll
        for (int q = 0; q < 4; ++q) {
            int sq = r0 + w * 16 + lq * 4 + q;
            mr[q] = (sq < M) ? memb[off + sq] : -1;
            pmin[q] = __builtin_inff();
        }

        for (int c0 = 0; c0 < M; c0 += COLT) {
            __syncthreads();
            for (int u = t; u < 1024; u += 256) {
                int cc = u >> 4, kb = u & 15;
                int cs = c0 + cc;
                int crow = memb[off + (cs < M ? cs : M - 1)];
                int4v v = *(const int4v*)(ebf + (size_t)crow * DD + kb * 8);
                int byte = (cc << 8) + (kb << 4);
                byte ^= (cc & 7) << 4;
                *(int4v*)((char*)Bs + byte) = v;
            }
            if (t < COLT) mcol[t] = (c0 + t < M) ? memb[off + c0 + t] : -1;
            __syncthreads();

#pragma unroll
            for (int cf = 0; cf < 4; ++cf) {
                const int cc = cf * 16 + l15;
                short8v bfrag[4];
#pragma unroll
                for (int ks = 0; ks < 4; ++ks) {
                    int byte = (cc << 8) + ks * 64 + lq * 16;
                    byte ^= (cc & 7) << 4;
                    bfrag[ks] = *(const short8v*)((const char*)Bs + byte);
                }
                f32x4 acc = { 0.f, 0.f, 0.f, 0.f };
#pragma unroll
                for (int ks = 0; ks < 4; ++ks)
                    acc = __builtin_amdgcn_mfma_f32_16x16x32_bf16(afrag[ks], bfrag[ks], acc, 0, 0, 0);
                const int mc = mcol[cf * 16 + l15];
#pragma unroll
                for (int q = 0; q < 4; ++q) {
                    float sv = (mc >= 0 && mc != mr[q]) ? acc[q] : __builtin_inff();
                    pmin[q] = fminf(pmin[q], sv);
                }
            }
        }

#pragma unroll
        for (int q = 0; q < 4; ++q) {
            float m = pmin[q];
#pragma unroll
            for (int d = 1; d < 16; d <<= 1) m = fminf(m, __shfl_xor(m, d));
            if (l15 == 0 && mr[q] >= 0) pos_min[mr[q]] = m;
        }
    }
}

// ---------------- K2: MFMA main pass, 128-row tiles, double-buffered pipeline ----------------
__global__ __launch_bounds__(256) void k2_main(const unsigned short* __restrict__ ebf,
                                               const int* __restrict__ lab,
                                               const float* __restrict__ pos_min,
                                               float* __restrict__ nmax_part,
                                               float* __restrict__ nsum_part) {
    __shared__ __align__(16) unsigned short Bs[2][COLT * DD];   // 2 x 16 KB
    __shared__ int labs[2][COLT];

    const int rb = blockIdx.x / NSPLIT;
    const int split = blockIdx.x % NSPLIT;
    const int row0 = rb * ROWT;
    const int col0 = split * CPS;
    const int t = threadIdx.x;
    const int w = t >> 6;
    const int l = t & 63;
    const int l15 = l & 15;
    const int lq = l >> 4;

    // two 64-row strips per block; wave w owns rows row0 + s*64 + w*16 + ...
    short8v afrag[2][4];
#pragma unroll
    for (int s = 0; s < 2; ++s) {
        const int arow = row0 + s * 64 + w * 16 + l15;
#pragma unroll
        for (int ks = 0; ks < 4; ++ks)
            afrag[s][ks] = *(const short8v*)(ebf + (size_t)arow * DD + ks * 32 + lq * 8);
    }

    float thr[2][4]; int labr[2][4];
    float nmax[2][4], nsum[2][4];
#pragma unroll
    for (int s = 0; s < 2; ++s)
#pragma unroll
        for (int q = 0; q < 4; ++q) {
            int r = row0 + s * 64 + w * 16 + lq * 4 + q;
            thr[s][q] = pos_min[r] - MARGIN;
            labr[s][q] = lab[r];
            nmax[s][q] = -__builtin_inff();
            nsum[s][q] = 0.f;
        }

    const int NT = CPS / COLT;   // 8 tiles
    int4v stg[4]; int stglab;

    // prologue: tile 0 -> buffer 0
    {
        const int cbase = col0;
#pragma unroll
        for (int k = 0; k < 4; ++k) {
            int u = t + k * 256, cc = u >> 4, kb = u & 15;
            stg[k] = *(const int4v*)(ebf + (size_t)(cbase + cc) * DD + kb * 8);
        }
        stglab = lab[cbase + (t & (COLT - 1))];
#pragma unroll
        for (int k = 0; k < 4; ++k) {
            int u = t + k * 256, cc = u >> 4, kb = u & 15;
            int byte = (cc << 8) + (kb << 4);
            byte ^= (cc & 7) << 4;
            *(int4v*)((char*)&Bs[0][0] + byte) = stg[k];
        }
        if (t < COLT) labs[0][t] = stglab;
    }

    int cur = 0;
    for (int tt = 0; tt < NT; ++tt) {
        __syncthreads();   // Bs[cur] ready; prior reads of Bs[cur^1] done

        if (tt + 1 < NT) {   // issue next tile's global loads
            const int cbase = col0 + (tt + 1) * COLT;
#pragma unroll
            for (int k = 0; k < 4; ++k) {
                int u = t + k * 256, cc = u >> 4, kb = u & 15;
                stg[k] = *(const int4v*)(ebf + (size_t)(cbase + cc) * DD + kb * 8);
            }
            stglab = lab[cbase + (t & (COLT - 1))];
        }

        const char* bsc = (const char*)&Bs[cur][0];
#pragma unroll
        for (int cf = 0; cf < 4; ++cf) {
            const int cc = cf * 16 + l15;
            short8v bfrag[4];
#pragma unroll
            for (int ks = 0; ks < 4; ++ks) {
                int byte = (cc << 8) + ks * 64 + lq * 16;
                byte ^= (cc & 7) << 4;
                bfrag[ks] = *(const short8v*)(bsc + byte);
            }
            f32x4 acc0 = { 0.f, 0.f, 0.f, 0.f };
            f32x4 acc1 = { 0.f, 0.f, 0.f, 0.f };
#pragma unroll
            for (int ks = 0; ks < 4; ++ks) {
                acc0 = __builtin_amdgcn_mfma_f32_16x16x32_bf16(afrag[0][ks], bfrag[ks], acc0, 0, 0, 0);
                acc1 = __builtin_amdgcn_mfma_f32_16x16x32_bf16(afrag[1][ks], bfrag[ks], acc1, 0, 0, 0);
            }

            const int labc = labs[cur][cf * 16 + l15];
#pragma unroll
            for (int q = 0; q < 4; ++q) {
                float s0 = acc0[q];
                float sv0 = (labc != labr[0][q] && s0 > thr[0][q]) ? s0 : -__builtin_inff();
                nmax[0][q] = fmaxf(nmax[0][q], sv0);
                nsum[0][q] += exp2_fast(fmaf(sv0, NEG_K1, NEG_K0));
                float s1 = acc1[q];
                float sv1 = (labc != labr[1][q] && s1 > thr[1][q]) ? s1 : -__builtin_inff();
                nmax[1][q] = fmaxf(nmax[1][q], sv1);
                nsum[1][q] += exp2_fast(fmaf(sv1, NEG_K1, NEG_K0));
            }
        }

        if (tt + 1 < NT) {   // write next tile into the other buffer
#pragma unroll
            for (int k = 0; k < 4; ++k) {
                int u = t + k * 256, cc = u >> 4, kb = u & 15;
                int byte = (cc << 8) + (kb << 4);
                byte ^= (cc & 7) << 4;
                *(int4v*)((char*)&Bs[cur ^ 1][0] + byte) = stg[k];
            }
            if (t < COLT) labs[cur ^ 1][t] = stglab;
        }
        cur ^= 1;
    }

#pragma unroll
    for (int s = 0; s < 2; ++s)
#pragma unroll
    for (int q = 0; q < 4; ++q) {
        float m = nmax[s][q], sm = nsum[s][q];
#pragma unroll
        for (int d = 1; d < 16; d <<= 1) {
            m = fmaxf(m, __shfl_xor(m, d));
            sm += __shfl_xor(sm, d);
        }
        if (l15 == 0) {
            int r = row0 + s * 64 + w * 16 + lq * 4 + q;
            nmax_part[(size_t)r * NSPLIT + split] = m;
            nsum_part[(size_t)r * NSPLIT + split] = sm;
        }
    }
}

// ---------------- K3c: per-class pos_sum + per-block (loss,cnt) partials ----------------
__global__ __launch_bounds__(256) void k3_class(const unsigned short* __restrict__ ebf,
                                                const int* __restrict__ offsets,
                                                const int* __restrict__ memb,
                                                const float* __restrict__ nmax_part,
                                                const float* __restrict__ nsum_part,
                                                float* __restrict__ part_loss,
                                                float* __restrict__ part_cnt) {
    __shared__ __align__(16) unsigned short Bs[COLT * DD];
    __shared__ int mcol[COLT];
    __shared__ float redl[256], redc[256];
    const int c = blockIdx.x & (NC - 1);
    const int rs = blockIdx.x >> 6;
    const int off = offsets[c];
    const int M = offsets[c + 1] - off;
    const int t = threadIdx.x, w = t >> 6, l = t & 63, l15 = l & 15, lq = l >> 4;

    float loss_acc = 0.f, cnt_acc = 0.f;

    if (M > 0)
    for (int r0 = rs * 64; r0 < M; r0 += 128) {
        const int slot_a = r0 + w * 16 + l15;
        const int arow = memb[off + (slot_a < M ? slot_a : M - 1)];
        short8v afrag[4];
#pragma unroll
        for (int ks = 0; ks < 4; ++ks)
            afrag[ks] = *(const short8v*)(ebf + (size_t)arow * DD + ks * 32 + lq * 8);

        int mr[4]; float pthr[4], nmv[4], nsv[4], psum[4];
#pragma unroll
        for (int q = 0; q < 4; ++q) {
            int sq = r0 + w * 16 + lq * 4 + q;
            mr[q] = (sq < M) ? memb[off + sq] : -1;
            psum[q] = 0.f;
            float nm = -__builtin_inff(), ns = 0.f;
            if (mr[q] >= 0) {
#pragma unroll
                for (int p = 0; p < NSPLIT; ++p) {
                    nm = fmaxf(nm, nmax_part[(size_t)mr[q] * NSPLIT + p]);
                    ns += nsum_part[(size_t)mr[q] * NSPLIT + p];
                }
            }
            nmv[q] = nm; nsv[q] = ns;
            pthr[q] = nm + MARGIN;   // -inf stays -inf -> no pos kept
        }

        for (int c0 = 0; c0 < M; c0 += COLT) {
            __syncthreads();
            for (int u = t; u < 1024; u += 256) {
                int cc = u >> 4, kb = u & 15;
                int cs = c0 + cc;
                int crow = memb[off + (cs < M ? cs : M - 1)];
                int4v v = *(const int4v*)(ebf + (size_t)crow * DD + kb * 8);
                int byte = (cc << 8) + (kb << 4);
                byte ^= (cc & 7) << 4;
                *(int4v*)((char*)Bs + byte) = v;
            }
            if (t < COLT) mcol[t] = (c0 + t < M) ? memb[off + c0 + t] : -1;
            __syncthreads();

#pragma unroll
            for (int cf = 0; cf < 4; ++cf) {
                const int cc = cf * 16 + l15;
                short8v bfrag[4];
#pragma unroll
                for (int ks = 0; ks < 4; ++ks) {
                    int byte = (cc << 8) + ks * 64 + lq * 16;
                    byte ^= (cc & 7) << 4;
                    bfrag[ks] = *(const short8v*)((const char*)Bs + byte);
                }
                f32x4 acc = { 0.f, 0.f, 0.f, 0.f };
#pragma unroll
                for (int ks = 0; ks < 4; ++ks)
                    acc = __builtin_amdgcn_mfma_f32_16x16x32_bf16(afrag[ks], bfrag[ks], acc, 0, 0, 0);
                const int mc = mcol[cf * 16 + l15];
#pragma unroll
                for (int q = 0; q < 4; ++q) {
                    float s = acc[q];
                    // mask to +inf: exp2(fma(+inf, NEG, POS)) = exp2(-inf) = 0
                    float sv = (mc >= 0 && mc != mr[q] && s < pthr[q]) ? s : __builtin_inff();
                    psum[q] += exp2_fast(fmaf(sv, POS_K1, POS_K0));
                }
            }
        }

#pragma unroll
        for (int q = 0; q < 4; ++q) {
            float ps = psum[q];
#pragma unroll
            for (int d = 1; d < 16; d <<= 1) ps += __shfl_xor(ps, d);
            if (l15 == 0 && mr[q] >= 0) {
                bool valid = (M >= 2) && (M < BN) && (nmv[q] > -3.0e38f) && (ps > 0.f);
                float loss = log1pf(ps) / ALPHA + log1pf(nsv[q]) / BETA;
                loss_acc += valid ? loss : 0.f;
                cnt_acc  += valid ? 1.f : 0.f;
            }
        }
    }

    __syncthreads();
    redl[t] = loss_acc; redc[t] = cnt_acc;
    __syncthreads();
    for (int s = 128; s > 0; s >>= 1) {
        if (t < s) { redl[t] += redl[t + s]; redc[t] += redc[t + s]; }
        __syncthreads();
    }
    if (t == 0) { part_loss[blockIdx.x] = redl[0]; part_cnt[blockIdx.x] = redc[0]; }
}

// ---------------- K4: final deterministic reduction over 128 partials ----------------
__global__ __launch_bounds__(128) void k4_final(const float* __restrict__ part_loss,
                                                const float* __restrict__ part_cnt,
                                                float* __restrict__ out) {
    __shared__ float rl[128], rc[128];
    const int t = threadIdx.x;
    rl[t] = part_loss[t]; rc[t] = part_cnt[t];
    __syncthreads();
    for (int s = 64; s > 0; s >>= 1) {
        if (t < s) { rl[t] += rl[t + s]; rc[t] += rc[t + s]; }
        __syncthreads();
    }
    if (t == 0) out[0] = (rc[0] > 0.f) ? rl[0] / fmaxf(rc[0], 1.f) : 0.f;
}

extern "C" void kernel_launch(void* const* d_in, const int* in_sizes, int n_in,
                              void* d_out, int out_size, void* d_ws, size_t ws_size,
                              hipStream_t stream) {
    const float* emb = (const float*)d_in[0];
    const int* lab = (const int*)d_in[1];
    float* out = (float*)d_out;

    char* ws = (char*)d_ws;
    unsigned short* ebf = (unsigned short*)ws;                   // 2 MB
    float* pos_min   = (float*)(ws + (size_t)BN * DD * 2);
    float* nmax_part = pos_min + BN;
    float* nsum_part = nmax_part + (size_t)BN * NSPLIT;
    float* part_loss = nsum_part + (size_t)BN * NSPLIT;          // NC*2
    float* part_cnt  = part_loss + NC * 2;
    int*   offsets   = (int*)(part_cnt + NC * 2);                // NC+1
    int*   memb      = offsets + (NC + 1);                       // BN

    k0_fused<<<BN * DD / 1024 + NC, 256, 0, stream>>>(emb, lab, ebf, offsets, memb);
    k1_class<<<NC * 2, 256, 0, stream>>>(ebf, offsets, memb, pos_min);
    k2_main<<<(BN / ROWT) * NSPLIT, 256, 0, stream>>>(ebf, lab, pos_min, nmax_part, nsum_part);
    k3_class<<<NC * 2, 256, 0, stream>>>(ebf, offsets, memb, nmax_part, nsum_part, part_loss, part_cnt);
    k4_final<<<1, 128, 0, stream>>>(part_loss, part_cnt, out);
}

// Round 8
// 93.179 us; speedup vs baseline: 13.6895x; 1.0782x over previous
//
#include <hip/hip_runtime.h>

#define BN 8192
#define DD 128
#define NC 64
#define ALPHA 2.0f
#define BETA 50.0f
#define BASE 0.5f
#define MARGIN 0.1f
#define ROWT 128
#define COLT 64
#define NSPLIT 16
#define CPS (BN / NSPLIT)
#define NEGBLKS ((BN / ROWT) * NSPLIT)   /* 1024 */
#define CLSBLKS (NC * 2)                 /* 128 */
#define SCALE_D 4294967296.0             /* 2^32 fixed-point for deterministic atomics */

// exp/exp2 folding: exp(B*(s-BASE)) = exp2(fma(s, B*log2e, -B*BASE*log2e))
#define NEG_K1 72.13475204444817f
#define NEG_K0 -36.067376022224085f
#define POS_K1 -2.8853900817779268f
#define POS_K0 1.4426950408889634f

typedef __attribute__((ext_vector_type(8))) short short8v;
typedef __attribute__((ext_vector_type(4))) float f32x4;
typedef __attribute__((ext_vector_type(4))) int int4v;

__device__ __forceinline__ float exp2_fast(float x) {
#if __has_builtin(__builtin_amdgcn_exp2f)
    return __builtin_amdgcn_exp2f(x);
#else
    return __expf(x * 0.6931471805599453f);
#endif
}

__device__ __forceinline__ unsigned short f2bf(float x) {
    union { float f; unsigned u; } q; q.f = x;
    unsigned r = q.u + 0x7fffu + ((q.u >> 16) & 1u);   // RNE
    return (unsigned short)(r >> 16);
}

// ---------------- K0: cvt (blocks 0..1023) + bucketing (1024..1087) + accum zeroing ----------------
__global__ __launch_bounds__(256) void k0_fused(const float* __restrict__ emb,
                                                const int* __restrict__ lab,
                                                unsigned short* __restrict__ ebf,
                                                int* __restrict__ offsets,
                                                int* __restrict__ memb,
                                                unsigned long long* __restrict__ accums) {
    const int b = blockIdx.x;
    const int t = threadIdx.x;
    if (b < BN * DD / 1024) {
        int idx = (b * 256 + t) * 4;
        float4 v = *(const float4*)(emb + idx);
        ushort4 o;
        o.x = f2bf(v.x); o.y = f2bf(v.y); o.z = f2bf(v.z); o.w = f2bf(v.w);
        *(ushort4*)(ebf + idx) = o;
        return;
    }
    const int c = b - BN * DD / 1024;
    if (c == 0 && t >= 64 && t < 67) accums[t - 64] = 0ull;   // loss, cnt, done
    if (t < 64) {
        int below = 0;
        for (int j = t; j < BN; j += 64) below += (lab[j] < c) ? 1 : 0;
#pragma unroll
        for (int d = 1; d < 64; d <<= 1) below += __shfl_xor(below, d);
        if (t == 0) {
            offsets[c] = below;
            if (c == 0) offsets[NC] = BN;
        }
        int cur = below;
        for (int j0 = 0; j0 < BN; j0 += 64) {
            const bool m = (lab[j0 + t] == c);
            unsigned long long bal = __ballot(m);
            int bel = __popcll(bal & ((1ULL << t) - 1ULL));
            if (m) memb[cur + bel] = j0 + t;
            cur += __popcll(bal);
        }
    }
}

// ---------------- K2b: neg pass (blocks 0..1023) + per-class pos_min (1024..1151) ----------------
__global__ __launch_bounds__(256) void k2b(const unsigned short* __restrict__ ebf,
                                           const int* __restrict__ lab,
                                           const int* __restrict__ offsets,
                                           const int* __restrict__ memb,
                                           float* __restrict__ nmax_part,
                                           float* __restrict__ nsum_part,
                                           float* __restrict__ pos_min) {
    __shared__ __align__(16) unsigned short Bs[2][COLT * DD];   // 2 x 16 KB
    __shared__ int labs[2][COLT];

    const int t = threadIdx.x;
    const int w = t >> 6;
    const int l = t & 63;
    const int l15 = l & 15;
    const int lq = l >> 4;

    if (blockIdx.x >= NEGBLKS) {
        // ---- pos_min class blocks ----
        const int bid = blockIdx.x - NEGBLKS;
        const int c = bid & (NC - 1);
        const int rs = bid >> 6;
        const int off = offsets[c];
        const int M = offsets[c + 1] - off;
        if (M == 0) return;
        unsigned short* B1 = &Bs[0][0];
        int* mcol = &labs[0][0];

        for (int r0 = rs * 64; r0 < M; r0 += 128) {
            const int slot_a = r0 + w * 16 + l15;
            const int arow = memb[off + (slot_a < M ? slot_a : M - 1)];
            short8v afrag[4];
#pragma unroll
            for (int ks = 0; ks < 4; ++ks)
                afrag[ks] = *(const short8v*)(ebf + (size_t)arow * DD + ks * 32 + lq * 8);

            int mr[4]; float pmin[4];
#pragma unroll
            for (int q = 0; q < 4; ++q) {
                int sq = r0 + w * 16 + lq * 4 + q;
                mr[q] = (sq < M) ? memb[off + sq] : -1;
                pmin[q] = __builtin_inff();
            }

            for (int c0 = 0; c0 < M; c0 += COLT) {
                __syncthreads();
                for (int u = t; u < 1024; u += 256) {
                    int cc = u >> 4, kb = u & 15;
                    int cs = c0 + cc;
                    int crow = memb[off + (cs < M ? cs : M - 1)];
                    int4v v = *(const int4v*)(ebf + (size_t)crow * DD + kb * 8);
                    int byte = (cc << 8) + (kb << 4);
                    byte ^= (cc & 7) << 4;
                    *(int4v*)((char*)B1 + byte) = v;
                }
                if (t < COLT) mcol[t] = (c0 + t < M) ? memb[off + c0 + t] : -1;
                __syncthreads();

#pragma unroll
                for (int cf = 0; cf < 4; ++cf) {
                    const int cc = cf * 16 + l15;
                    short8v bfrag[4];
#pragma unroll
                    for (int ks = 0; ks < 4; ++ks) {
                        int byte = (cc << 8) + ks * 64 + lq * 16;
                        byte ^= (cc & 7) << 4;
                        bfrag[ks] = *(const short8v*)((const char*)B1 + byte);
                    }
                    f32x4 acc = { 0.f, 0.f, 0.f, 0.f };
#pragma unroll
                    for (int ks = 0; ks < 4; ++ks)
                        acc = __builtin_amdgcn_mfma_f32_16x16x32_bf16(afrag[ks], bfrag[ks], acc, 0, 0, 0);
                    const int mc = mcol[cf * 16 + l15];
#pragma unroll
                    for (int q = 0; q < 4; ++q) {
                        float sv = (mc >= 0 && mc != mr[q]) ? acc[q] : __builtin_inff();
                        pmin[q] = fminf(pmin[q], sv);
                    }
                }
            }

#pragma unroll
            for (int q = 0; q < 4; ++q) {
                float m = pmin[q];
#pragma unroll
                for (int d = 1; d < 16; d <<= 1) m = fminf(m, __shfl_xor(m, d));
                if (l15 == 0 && mr[q] >= 0) pos_min[mr[q]] = m;
            }
        }
        return;
    }

    // ---- neg pass: full Gram, unthresholded nsum/nmax (class-masked only) ----
    const int rb = blockIdx.x / NSPLIT;
    const int split = blockIdx.x % NSPLIT;
    const int row0 = rb * ROWT;
    const int col0 = split * CPS;

    short8v afrag[2][4];
#pragma unroll
    for (int s = 0; s < 2; ++s) {
        const int arow = row0 + s * 64 + w * 16 + l15;
#pragma unroll
        for (int ks = 0; ks < 4; ++ks)
            afrag[s][ks] = *(const short8v*)(ebf + (size_t)arow * DD + ks * 32 + lq * 8);
    }

    int labr[2][4];
    float nmax[2][4], nsum[2][4];
#pragma unroll
    for (int s = 0; s < 2; ++s)
#pragma unroll
        for (int q = 0; q < 4; ++q) {
            int r = row0 + s * 64 + w * 16 + lq * 4 + q;
            labr[s][q] = lab[r];
            nmax[s][q] = -__builtin_inff();
            nsum[s][q] = 0.f;
        }

    const int NT = CPS / COLT;   // 8 tiles
    int4v stg[4]; int stglab;

    {   // prologue: tile 0 -> buffer 0
        const int cbase = col0;
#pragma unroll
        for (int k = 0; k < 4; ++k) {
            int u = t + k * 256, cc = u >> 4, kb = u & 15;
            stg[k] = *(const int4v*)(ebf + (size_t)(cbase + cc) * DD + kb * 8);
        }
        stglab = lab[cbase + (t & (COLT - 1))];
#pragma unroll
        for (int k = 0; k < 4; ++k) {
            int u = t + k * 256, cc = u >> 4, kb = u & 15;
            int byte = (cc << 8) + (kb << 4);
            byte ^= (cc & 7) << 4;
            *(int4v*)((char*)&Bs[0][0] + byte) = stg[k];
        }
        if (t < COLT) labs[0][t] = stglab;
    }

    int cur = 0;
    for (int tt = 0; tt < NT; ++tt) {
        __syncthreads();

        if (tt + 1 < NT) {
            const int cbase = col0 + (tt + 1) * COLT;
#pragma unroll
            for (int k = 0; k < 4; ++k) {
                int u = t + k * 256, cc = u >> 4, kb = u & 15;
                stg[k] = *(const int4v*)(ebf + (size_t)(cbase + cc) * DD + kb * 8);
            }
            stglab = lab[cbase + (t & (COLT - 1))];
        }

        const char* bsc = (const char*)&Bs[cur][0];
#pragma unroll
        for (int cf = 0; cf < 4; ++cf) {
            const int cc = cf * 16 + l15;
            short8v bfrag[4];
#pragma unroll
            for (int ks = 0; ks < 4; ++ks) {
                int byte = (cc << 8) + ks * 64 + lq * 16;
                byte ^= (cc & 7) << 4;
                bfrag[ks] = *(const short8v*)(bsc + byte);
            }
            f32x4 acc0 = { 0.f, 0.f, 0.f, 0.f };
            f32x4 acc1 = { 0.f, 0.f, 0.f, 0.f };
#pragma unroll
            for (int ks = 0; ks < 4; ++ks) {
                acc0 = __builtin_amdgcn_mfma_f32_16x16x32_bf16(afrag[0][ks], bfrag[ks], acc0, 0, 0, 0);
                acc1 = __builtin_amdgcn_mfma_f32_16x16x32_bf16(afrag[1][ks], bfrag[ks], acc1, 0, 0, 0);
            }

            const int labc = labs[cur][cf * 16 + l15];
#pragma unroll
            for (int q = 0; q < 4; ++q) {
                float sv0 = (labc != labr[0][q]) ? acc0[q] : -__builtin_inff();
                nmax[0][q] = fmaxf(nmax[0][q], sv0);
                nsum[0][q] += exp2_fast(fmaf(sv0, NEG_K1, NEG_K0));
                float sv1 = (labc != labr[1][q]) ? acc1[q] : -__builtin_inff();
                nmax[1][q] = fmaxf(nmax[1][q], sv1);
                nsum[1][q] += exp2_fast(fmaf(sv1, NEG_K1, NEG_K0));
            }
        }

        if (tt + 1 < NT) {
#pragma unroll
            for (int k = 0; k < 4; ++k) {
                int u = t + k * 256, cc = u >> 4, kb = u & 15;
                int byte = (cc << 8) + (kb << 4);
                byte ^= (cc & 7) << 4;
                *(int4v*)((char*)&Bs[cur ^ 1][0] + byte) = stg[k];
            }
            if (t < COLT) labs[cur ^ 1][t] = stglab;
        }
        cur ^= 1;
    }

#pragma unroll
    for (int s = 0; s < 2; ++s)
#pragma unroll
    for (int q = 0; q < 4; ++q) {
        float m = nmax[s][q], sm = nsum[s][q];
#pragma unroll
        for (int d = 1; d < 16; d <<= 1) {
            m = fmaxf(m, __shfl_xor(m, d));
            sm += __shfl_xor(sm, d);
        }
        if (l15 == 0) {
            int r = row0 + s * 64 + w * 16 + lq * 4 + q;
            nmax_part[(size_t)r * NSPLIT + split] = m;
            nsum_part[(size_t)r * NSPLIT + split] = sm;
        }
    }
}

// ---------------- K3f: per-class pos_sum + loss + deterministic atomic finalize ----------------
__global__ __launch_bounds__(256) void k3_final(const unsigned short* __restrict__ ebf,
                                                const int* __restrict__ offsets,
                                                const int* __restrict__ memb,
                                                const float* __restrict__ nmax_part,
                                                const float* __restrict__ nsum_part,
                                                const float* __restrict__ pos_min,
                                                unsigned long long* __restrict__ accums,
                                                float* __restrict__ out) {
    __shared__ __align__(16) unsigned short Bs[COLT * DD];
    __shared__ int mcol[COLT];
    __shared__ float redl[256], redc[256];
    const int c = blockIdx.x & (NC - 1);
    const int rs = blockIdx.x >> 6;
    const int off = offsets[c];
    const int M = offsets[c + 1] - off;
    const int t = threadIdx.x, w = t >> 6, l = t & 63, l15 = l & 15, lq = l >> 4;

    float loss_acc = 0.f, cnt_acc = 0.f;

    if (M > 0)
    for (int r0 = rs * 64; r0 < M; r0 += 128) {
        const int slot_a = r0 + w * 16 + l15;
        const int arow = memb[off + (slot_a < M ? slot_a : M - 1)];
        short8v afrag[4];
#pragma unroll
        for (int ks = 0; ks < 4; ++ks)
            afrag[ks] = *(const short8v*)(ebf + (size_t)arow * DD + ks * 32 + lq * 8);

        int mr[4]; float pthr[4], nmv[4], nsv[4], pmv[4], psum[4];
#pragma unroll
        for (int q = 0; q < 4; ++q) {
            int sq = r0 + w * 16 + lq * 4 + q;
            mr[q] = (sq < M) ? memb[off + sq] : -1;
            psum[q] = 0.f;
            float nm = -__builtin_inff(), ns = 0.f;
            if (mr[q] >= 0) {
#pragma unroll
                for (int p = 0; p < NSPLIT; ++p) {
                    nm = fmaxf(nm, nmax_part[(size_t)mr[q] * NSPLIT + p]);
                    ns += nsum_part[(size_t)mr[q] * NSPLIT + p];
                }
            }
            nmv[q] = nm; nsv[q] = ns;
            pmv[q] = (mr[q] >= 0) ? pos_min[mr[q]] : 0.f;
            pthr[q] = nm + MARGIN;
        }

        for (int c0 = 0; c0 < M; c0 += COLT) {
            __syncthreads();
            for (int u = t; u < 1024; u += 256) {
                int cc = u >> 4, kb = u & 15;
                int cs = c0 + cc;
                int crow = memb[off + (cs < M ? cs : M - 1)];
                int4v v = *(const int4v*)(ebf + (size_t)crow * DD + kb * 8);
                int byte = (cc << 8) + (kb << 4);
                byte ^= (cc & 7) << 4;
                *(int4v*)((char*)Bs + byte) = v;
            }
            if (t < COLT) mcol[t] = (c0 + t < M) ? memb[off + c0 + t] : -1;
            __syncthreads();

#pragma unroll
            for (int cf = 0; cf < 4; ++cf) {
                const int cc = cf * 16 + l15;
                short8v bfrag[4];
#pragma unroll
                for (int ks = 0; ks < 4; ++ks) {
                    int byte = (cc << 8) + ks * 64 + lq * 16;
                    byte ^= (cc & 7) << 4;
                    bfrag[ks] = *(const short8v*)((const char*)Bs + byte);
                }
                f32x4 acc = { 0.f, 0.f, 0.f, 0.f };
#pragma unroll
                for (int ks = 0; ks < 4; ++ks)
                    acc = __builtin_amdgcn_mfma_f32_16x16x32_bf16(afrag[ks], bfrag[ks], acc, 0, 0, 0);
                const int mc = mcol[cf * 16 + l15];
#pragma unroll
                for (int q = 0; q < 4; ++q) {
                    float s = acc[q];
                    float sv = (mc >= 0 && mc != mr[q] && s < pthr[q]) ? s : __builtin_inff();
                    psum[q] += exp2_fast(fmaf(sv, POS_K1, POS_K0));
                }
            }
        }

#pragma unroll
        for (int q = 0; q < 4; ++q) {
            float ps = psum[q];
#pragma unroll
            for (int d = 1; d < 16; d <<= 1) ps += __shfl_xor(ps, d);
            if (l15 == 0 && mr[q] >= 0) {
                bool valid = (M >= 2) && (M < BN) && (nmv[q] > pmv[q] - MARGIN) && (ps > 0.f);
                float loss = log1pf(ps) / ALPHA + log1pf(nsv[q]) / BETA;
                loss_acc += valid ? loss : 0.f;
                cnt_acc  += valid ? 1.f : 0.f;
            }
        }
    }

    __syncthreads();
    redl[t] = loss_acc; redc[t] = cnt_acc;
    __syncthreads();
    for (int s = 128; s > 0; s >>= 1) {
        if (t < s) { redl[t] += redl[t + s]; redc[t] += redc[t + s]; }
        __syncthreads();
    }
    if (t == 0) {
        atomicAdd(&accums[0], (unsigned long long)((double)redl[0] * SCALE_D + 0.5));
        atomicAdd(&accums[1], (unsigned long long)(redc[0] + 0.5f));
        __threadfence();
        unsigned long long old = atomicAdd(&accums[2], 1ull);
        if (old == (unsigned long long)(CLSBLKS - 1)) {
            __threadfence();
            unsigned long long li = atomicAdd(&accums[0], 0ull);
            unsigned long long ci = atomicAdd(&accums[1], 0ull);
            double L = (double)li / SCALE_D;
            out[0] = (ci > 0ull) ? (float)(L / (double)ci) : 0.f;
        }
    }
}

extern "C" void kernel_launch(void* const* d_in, const int* in_sizes, int n_in,
                              void* d_out, int out_size, void* d_ws, size_t ws_size,
                              hipStream_t stream) {
    const float* emb = (const float*)d_in[0];
    const int* lab = (const int*)d_in[1];
    float* out = (float*)d_out;

    char* ws = (char*)d_ws;
    unsigned short* ebf = (unsigned short*)ws;                   // 2 MB
    float* pos_min   = (float*)(ws + (size_t)BN * DD * 2);
    float* nmax_part = pos_min + BN;
    float* nsum_part = nmax_part + (size_t)BN * NSPLIT;
    unsigned long long* accums = (unsigned long long*)(nsum_part + (size_t)BN * NSPLIT); // 3 ull, 8B-aligned
    int*   offsets   = (int*)(accums + 4);                       // NC+1
    int*   memb      = offsets + (NC + 1);                       // BN

    k0_fused<<<BN * DD / 1024 + NC, 256, 0, stream>>>(emb, lab, ebf, offsets, memb, accums);
    k2b<<<NEGBLKS + CLSBLKS, 256, 0, stream>>>(ebf, lab, offsets, memb, nmax_part, nsum_part, pos_min);
    k3_final<<<CLSBLKS, 256, 0, stream>>>(ebf, offsets, memb, nmax_part, nsum_part, pos_min, accums, out);
}